// Round 1
// baseline (560.258 us; speedup 1.0000x reference)
//
#include <hip/hip_runtime.h>
#include <hip/hip_bf16.h>

// ON-LSTM cell, fused: gates = x@W_ih^T + b_ih + hx@W_hh^T + b_hh  (bf16 MFMA),
// cumulative-softmax master gates + LSTM elementwise fused into the epilogue.
// B=8192, IN=H=1024, NC=16, CS=64, K_total=2048.
//
// Tile: BM=128 rows x BNH=32 h-cols -> GEMM tile 128x128 (4 gates x 32 cols).
// Waves: 4 waves, each 32 rows x 128 cols => all 4 gates of (b,h) are lane-local.

#define B_ROWS 8192
#define IN_DIM 1024
#define H_DIM  1024
#define NCHUNK 16
#define K_TOT  2048

#define BM   128
#define BNH  32
#define BN   128
#define BK   64
#define NKT  (K_TOT / BK)   // 32
#define THREADS 256

typedef __attribute__((ext_vector_type(4))) float  f32x4;
typedef __bf16 bf16x4 __attribute__((ext_vector_type(4)));
typedef __bf16 bf16x8 __attribute__((ext_vector_type(8)));

__device__ __forceinline__ float sigmoidf_(float x) {
    return 1.0f / (1.0f + __expf(-x));
}
__device__ __forceinline__ float tanhf_(float x) {
    float e = __expf(-2.0f * fabsf(x));
    float t = (1.0f - e) / (1.0f + e);
    return copysignf(t, x);
}

__global__ __launch_bounds__(THREADS, 2)
void onlstm_fused(const float* __restrict__ x, const float* __restrict__ hx,
                  const float* __restrict__ cx,
                  const float* __restrict__ input_floor,
                  const float* __restrict__ forget_floor,
                  const float* __restrict__ W_ih, const float* __restrict__ b_ih,
                  const float* __restrict__ W_hh, const float* __restrict__ b_hh,
                  float* __restrict__ out)
{
    __shared__ __align__(16) __bf16 A_s[BM * BK];
    __shared__ __align__(16) __bf16 B_s[BN * BK];
    __shared__ float ci_s[BM], cf_s[BM], bias_s[BN];

    const int tid = threadIdx.x;
    const int bh  = blockIdx.x;        // 0..31  (h tile)
    const int bm  = blockIdx.y;        // 0..63  (row tile)
    const int h0  = bh * BNH;
    const int nc  = h0 >> 6;           // chunk index, constant per block

    // ---- prologue: per-block bias slice + per-row cumulative-softmax gates ----
    if (tid < BM) {
        {   // bias_s[g*32 + j] for tile column g*32+j  (weight row g*1024+h0+j)
            int g = tid >> 5, j = tid & 31;
            int wr = g * H_DIM + h0 + j;
            bias_s[tid] = b_ih[wr] + b_hh[wr];
        }
        int b = bm * BM + tid;
        const int off = (nc < 8) ? 0 : 8;
        const int ic  = (nc < 8) ? nc : (nc - 8);
        const float* pin = input_floor  + (size_t)b * NCHUNK + off;
        const float* pfg = forget_floor + (size_t)b * NCHUNK + off;
        float vi[8], vf[8];
        float mi = -1e30f, mf = -1e30f;
        #pragma unroll
        for (int t = 0; t < 8; ++t) {
            vi[t] = pin[t]; vf[t] = pfg[t];
            mi = fmaxf(mi, vi[t]); mf = fmaxf(mf, vf[t]);
        }
        float si = 0.f, sf = 0.f;
        #pragma unroll
        for (int t = 0; t < 8; ++t) {
            vi[t] = __expf(vi[t] - mi); vf[t] = __expf(vf[t] - mf);
            si += vi[t]; sf += vf[t];
        }
        float pi = 0.f, pf = 0.f;
        #pragma unroll
        for (int t = 0; t < 8; ++t) { if (t <= ic) { pi += vi[t]; pf += vf[t]; } }
        float suf_i = si - pi + vi[ic];   // inclusive suffix sum at ic
        float suf_f = sf - pf + vf[ic];
        float civ, cfv;
        if (nc < 8) { civ = pi / si;    cfv = suf_f / sf; }  // happy: cum / revcum
        else        { civ = suf_i / si; cfv = pf / sf;    }  // sad:   revcum / cum
        ci_s[tid] = civ; cf_s[tid] = cfv;
    }

    // ---- GEMM: 128x128 tile, K=2048 in steps of 64, bf16 16x16x32 MFMA ----
    f32x4 acc[2][8];
    #pragma unroll
    for (int i = 0; i < 2; ++i)
        #pragma unroll
        for (int j = 0; j < 8; ++j) acc[i][j] = (f32x4){0.f, 0.f, 0.f, 0.f};

    const int l  = tid & 63;
    const int w  = tid >> 6;     // wave 0..3 -> rows w*32..w*32+31
    const int lr = l & 15;
    const int lh = l >> 4;

    for (int kt = 0; kt < NKT; ++kt) {
        const float* Asrc; const float* Wsrc; int kb;
        if (kt < 16) { Asrc = x;  Wsrc = W_ih; kb = kt * BK; }
        else         { Asrc = hx; Wsrc = W_hh; kb = kt * BK - IN_DIM; }

        __syncthreads();   // previous tile's reads done
        // stage A: 128 rows x 64 f32 -> bf16, XOR-swizzled  (16 lanes per row)
        #pragma unroll
        for (int i = 0; i < 8; ++i) {
            int idx = tid + i * THREADS;       // 0..2047
            int row = idx >> 4;
            int k4  = (idx & 15) << 2;
            f32x4 v = *reinterpret_cast<const f32x4*>(
                Asrc + (size_t)(bm * BM + row) * IN_DIM + kb + k4);
            bf16x4 s4;
            s4.x = (__bf16)v.x; s4.y = (__bf16)v.y; s4.z = (__bf16)v.z; s4.w = (__bf16)v.w;
            *reinterpret_cast<bf16x4*>(&A_s[row * BK + (k4 ^ ((row & 7) << 3))]) = s4;
        }
        // stage B: tile col n -> weight row (n>>5)*1024 + h0 + (n&31)
        #pragma unroll
        for (int i = 0; i < 8; ++i) {
            int idx  = tid + i * THREADS;
            int nrow = idx >> 4;
            int k4   = (idx & 15) << 2;
            int wr   = (nrow >> 5) * H_DIM + h0 + (nrow & 31);
            f32x4 v = *reinterpret_cast<const f32x4*>(
                Wsrc + (size_t)wr * IN_DIM + kb + k4);
            bf16x4 s4;
            s4.x = (__bf16)v.x; s4.y = (__bf16)v.y; s4.z = (__bf16)v.z; s4.w = (__bf16)v.w;
            *reinterpret_cast<bf16x4*>(&B_s[nrow * BK + (k4 ^ ((nrow & 7) << 3))]) = s4;
        }
        __syncthreads();

        #pragma unroll
        for (int s = 0; s < 2; ++s) {
            const int kf = s * 32 + lh * 8;
            bf16x8 a0, a1;
            {
                int row = w * 32 + lr;
                a0 = *reinterpret_cast<const bf16x8*>(&A_s[row * BK + (kf ^ ((row & 7) << 3))]);
                row += 16;
                a1 = *reinterpret_cast<const bf16x8*>(&A_s[row * BK + (kf ^ ((row & 7) << 3))]);
            }
            #pragma unroll
            for (int fn = 0; fn < 8; ++fn) {
                int nrow = fn * 16 + lr;
                bf16x8 bb = *reinterpret_cast<const bf16x8*>(
                    &B_s[nrow * BK + (kf ^ ((nrow & 7) << 3))]);
                acc[0][fn] = __builtin_amdgcn_mfma_f32_16x16x32_bf16(a0, bb, acc[0][fn], 0, 0, 0);
                acc[1][fn] = __builtin_amdgcn_mfma_f32_16x16x32_bf16(a1, bb, acc[1][fn], 0, 0, 0);
            }
        }
    }

    // ---- epilogue: all 4 gates for (b,h) are in this lane ----
    const size_t CY_OFF = (size_t)B_ROWS * H_DIM;
    #pragma unroll
    for (int fm = 0; fm < 2; ++fm) {
        #pragma unroll
        for (int r = 0; r < 4; ++r) {
            int rt = w * 32 + fm * 16 + lh * 4 + r;   // C/D: row=(lane>>4)*4+reg
            int b  = bm * BM + rt;
            float civ = ci_s[rt], cfv = cf_s[rt];
            float ovl = cfv * civ;
            #pragma unroll
            for (int p = 0; p < 2; ++p) {
                int j = p * 16 + lr;                  // C/D: col = lane&15
                int h = h0 + j;
                float og = acc[fm][0 + p][r] + bias_s[j];
                float cg = acc[fm][2 + p][r] + bias_s[32 + j];
                float ig = acc[fm][4 + p][r] + bias_s[64 + j];
                float fg = acc[fm][6 + p][r] + bias_s[96 + j];
                float i_s = sigmoidf_(ig);
                float f_s = sigmoidf_(fg);
                float c_t = tanhf_(cg);
                float o_s = sigmoidf_(og);
                float fq = f_s * ovl + (cfv - ovl);
                float iq = i_s * ovl + (civ - ovl);
                float cxv = cx[(size_t)b * H_DIM + h];
                float cyv = fq * cxv + iq * c_t;
                float hyv = o_s * tanhf_(cyv);
                out[(size_t)b * H_DIM + h] = hyv;
                out[CY_OFF + (size_t)b * H_DIM + h] = cyv;
            }
        }
    }
}

extern "C" void kernel_launch(void* const* d_in, const int* in_sizes, int n_in,
                              void* d_out, int out_size, void* d_ws, size_t ws_size,
                              hipStream_t stream) {
    const float* x            = (const float*)d_in[0];
    const float* hx           = (const float*)d_in[1];
    const float* cx           = (const float*)d_in[2];
    const float* input_floor  = (const float*)d_in[3];
    const float* forget_floor = (const float*)d_in[4];
    const float* W_ih         = (const float*)d_in[5];
    const float* b_ih         = (const float*)d_in[6];
    const float* W_hh         = (const float*)d_in[7];
    const float* b_hh         = (const float*)d_in[8];
    float* out = (float*)d_out;

    dim3 grid(H_DIM / BNH, B_ROWS / BM);   // (32, 64)
    onlstm_fused<<<grid, THREADS, 0, stream>>>(
        x, hx, cx, input_floor, forget_floor, W_ih, b_ih, W_hh, b_hh, out);
}

// Round 2
// 169.015 us; speedup vs baseline: 3.3148x; 3.3148x over previous
//
#include <hip/hip_runtime.h>
#include <hip/hip_bf16.h>

// ON-LSTM cell, fused. R2: pre-pack x|hx and W into bf16 in d_ws, then
// MFMA GEMM with global_load_lds(16B) staging (pre-swizzled global source,
// linear LDS dest) + fused cumsoftmax/LSTM epilogue.

#define B_ROWS 8192
#define IN_DIM 1024
#define H_DIM  1024
#define NCHUNK 16
#define K_TOT  2048

#define BM   128
#define BNH  32
#define BN   128
#define BK   64
#define NKT  (K_TOT / BK)   // 32
#define THREADS 256

#define A_PACK_ELEMS ((size_t)B_ROWS * K_TOT)            // 16,777,216
#define W_PACK_ELEMS ((size_t)32 * 128 * K_TOT)          //  8,388,608
#define A_PACK_BYTES (A_PACK_ELEMS * 2)                  // 33,554,432
#define W_PACK_BYTES (W_PACK_ELEMS * 2)                  // 16,777,216

typedef __attribute__((ext_vector_type(4))) float  f32x4;
typedef __bf16 bf16x4 __attribute__((ext_vector_type(4)));
typedef __bf16 bf16x8 __attribute__((ext_vector_type(8)));

__device__ __forceinline__ float sigmoidf_(float x) {
    return 1.0f / (1.0f + __expf(-x));
}
__device__ __forceinline__ float tanhf_(float x) {
    float e = __expf(-2.0f * fabsf(x));
    float t = (1.0f - e) / (1.0f + e);
    return copysignf(t, x);
}

__device__ __forceinline__ void gload16(const __bf16* gsrc, __bf16* lds_dst) {
    __builtin_amdgcn_global_load_lds(
        (const __attribute__((address_space(1))) unsigned int*)gsrc,
        (__attribute__((address_space(3))) unsigned int*)lds_dst, 16, 0, 0);
}

__device__ __forceinline__ bf16x8 cvt8(f32x4 v0, f32x4 v1) {
    bf16x8 o;
    o[0] = (__bf16)v0.x; o[1] = (__bf16)v0.y; o[2] = (__bf16)v0.z; o[3] = (__bf16)v0.w;
    o[4] = (__bf16)v1.x; o[5] = (__bf16)v1.y; o[6] = (__bf16)v1.z; o[7] = (__bf16)v1.w;
    return o;
}

// ---- pack [x | hx] -> bf16 Abf[8192][2048] ----
__global__ __launch_bounds__(256)
void pack_A(const float* __restrict__ x, const float* __restrict__ hx,
            __bf16* __restrict__ Abf)
{
    int idx = blockIdx.x * 256 + threadIdx.x;       // 0 .. 8192*256-1
    int row = idx >> 8;
    int c8  = (idx & 255) << 3;
    const float* src = (c8 < IN_DIM)
        ? (x  + (size_t)row * IN_DIM + c8)
        : (hx + (size_t)row * IN_DIM + (c8 - IN_DIM));
    f32x4 v0 = *reinterpret_cast<const f32x4*>(src);
    f32x4 v1 = *reinterpret_cast<const f32x4*>(src + 4);
    *reinterpret_cast<bf16x8*>(Abf + (size_t)row * K_TOT + c8) = cvt8(v0, v1);
}

// ---- pack W_ih|W_hh -> bf16 Wp[bh=32][nrow=128][2048] ----
// tile col nrow = g*32+j of block bh  ->  weight row g*1024 + bh*32 + j
__global__ __launch_bounds__(256)
void pack_W(const float* __restrict__ W_ih, const float* __restrict__ W_hh,
            __bf16* __restrict__ Wp)
{
    int idx  = blockIdx.x * 256 + threadIdx.x;      // 0 .. 32*128*256-1
    int k8   = (idx & 255) << 3;
    int nrow = (idx >> 8) & 127;
    int bh   = idx >> 15;
    int wr   = (nrow >> 5) * H_DIM + bh * BNH + (nrow & 31);
    const float* src = (k8 < IN_DIM)
        ? (W_ih + (size_t)wr * IN_DIM + k8)
        : (W_hh + (size_t)wr * IN_DIM + (k8 - IN_DIM));
    f32x4 v0 = *reinterpret_cast<const f32x4*>(src);
    f32x4 v1 = *reinterpret_cast<const f32x4*>(src + 4);
    *reinterpret_cast<bf16x8*>(Wp + ((size_t)bh * 128 + nrow) * K_TOT + k8) = cvt8(v0, v1);
}

// ---- main fused kernel ----
__global__ __launch_bounds__(THREADS, 4)
void onlstm_gemm(const __bf16* __restrict__ Abf, const __bf16* __restrict__ Wp,
                 const float* __restrict__ cx,
                 const float* __restrict__ input_floor,
                 const float* __restrict__ forget_floor,
                 const float* __restrict__ b_ih, const float* __restrict__ b_hh,
                 float* __restrict__ out)
{
    __shared__ __align__(16) __bf16 A_s[BM * BK];
    __shared__ __align__(16) __bf16 B_s[BN * BK];
    __shared__ float ci_s[BM], cf_s[BM], bias_s[BN];

    const int tid = threadIdx.x;
    const int bh  = blockIdx.x;        // 0..31
    const int bm  = blockIdx.y;        // 0..63
    const int h0  = bh * BNH;
    const int nc  = h0 >> 6;

    if (tid < BM) {
        {
            int g = tid >> 5, j = tid & 31;
            int wr = g * H_DIM + h0 + j;
            bias_s[tid] = b_ih[wr] + b_hh[wr];
        }
        int b = bm * BM + tid;
        const int off = (nc < 8) ? 0 : 8;
        const int ic  = (nc < 8) ? nc : (nc - 8);
        const float* pin = input_floor  + (size_t)b * NCHUNK + off;
        const float* pfg = forget_floor + (size_t)b * NCHUNK + off;
        float vi[8], vf[8];
        float mi = -1e30f, mf = -1e30f;
        #pragma unroll
        for (int t = 0; t < 8; ++t) {
            vi[t] = pin[t]; vf[t] = pfg[t];
            mi = fmaxf(mi, vi[t]); mf = fmaxf(mf, vf[t]);
        }
        float si = 0.f, sf = 0.f;
        #pragma unroll
        for (int t = 0; t < 8; ++t) {
            vi[t] = __expf(vi[t] - mi); vf[t] = __expf(vf[t] - mf);
            si += vi[t]; sf += vf[t];
        }
        float pi = 0.f, pf = 0.f;
        #pragma unroll
        for (int t = 0; t < 8; ++t) { if (t <= ic) { pi += vi[t]; pf += vf[t]; } }
        float suf_i = si - pi + vi[ic];
        float suf_f = sf - pf + vf[ic];
        float civ, cfv;
        if (nc < 8) { civ = pi / si;    cfv = suf_f / sf; }
        else        { civ = suf_i / si; cfv = pf / sf;    }
        ci_s[tid] = civ; cf_s[tid] = cfv;
    }

    f32x4 acc[2][8];
    #pragma unroll
    for (int i = 0; i < 2; ++i)
        #pragma unroll
        for (int j = 0; j < 8; ++j) acc[i][j] = (f32x4){0.f, 0.f, 0.f, 0.f};

    const int l  = tid & 63;
    const int w  = tid >> 6;
    const int lr = l & 15;
    const int lh = l >> 4;

    const __bf16* Wblk = Wp + (size_t)bh * 128 * K_TOT;
    const __bf16* Arow = Abf + (size_t)(bm * BM) * K_TOT;

    for (int kt = 0; kt < NKT; ++kt) {
        const int kb = kt * BK;
        __syncthreads();   // previous tile's LDS reads done
        // 16 gload_lds instrs (8/thread): linear LDS dest, swizzled global src
        #pragma unroll
        for (int i = 0; i < 4; ++i) {
            int e   = (w * 4 + i) * 512 + l * 8;   // element offset in tile
            int row = e >> 6;
            int kd  = e & 63;
            int ks  = kd ^ ((row & 7) << 3);
            gload16(Arow + (size_t)row * K_TOT + kb + ks, &A_s[(w * 4 + i) * 512]);
            gload16(Wblk + (size_t)row * K_TOT + kb + ks, &B_s[(w * 4 + i) * 512]);
        }
        __syncthreads();   // vmcnt(0) drain at barrier

        #pragma unroll
        for (int s = 0; s < 2; ++s) {
            const int kf = s * 32 + lh * 8;
            bf16x8 a0, a1;
            {
                int row = w * 32 + lr;
                a0 = *reinterpret_cast<const bf16x8*>(&A_s[row * BK + (kf ^ ((row & 7) << 3))]);
                row += 16;
                a1 = *reinterpret_cast<const bf16x8*>(&A_s[row * BK + (kf ^ ((row & 7) << 3))]);
            }
            #pragma unroll
            for (int fn = 0; fn < 8; ++fn) {
                int nrow = fn * 16 + lr;
                bf16x8 bb = *reinterpret_cast<const bf16x8*>(
                    &B_s[nrow * BK + (kf ^ ((nrow & 7) << 3))]);
                acc[0][fn] = __builtin_amdgcn_mfma_f32_16x16x32_bf16(a0, bb, acc[0][fn], 0, 0, 0);
                acc[1][fn] = __builtin_amdgcn_mfma_f32_16x16x32_bf16(a1, bb, acc[1][fn], 0, 0, 0);
            }
        }
    }

    const size_t CY_OFF = (size_t)B_ROWS * H_DIM;
    #pragma unroll
    for (int fm = 0; fm < 2; ++fm) {
        #pragma unroll
        for (int r = 0; r < 4; ++r) {
            int rt = w * 32 + fm * 16 + lh * 4 + r;
            int b  = bm * BM + rt;
            float civ = ci_s[rt], cfv = cf_s[rt];
            float ovl = cfv * civ;
            #pragma unroll
            for (int p = 0; p < 2; ++p) {
                int j = p * 16 + lr;
                int h = h0 + j;
                float og = acc[fm][0 + p][r] + bias_s[j];
                float cg = acc[fm][2 + p][r] + bias_s[32 + j];
                float ig = acc[fm][4 + p][r] + bias_s[64 + j];
                float fg = acc[fm][6 + p][r] + bias_s[96 + j];
                float i_s = sigmoidf_(ig);
                float f_s = sigmoidf_(fg);
                float c_t = tanhf_(cg);
                float o_s = sigmoidf_(og);
                float fq = f_s * ovl + (cfv - ovl);
                float iq = i_s * ovl + (civ - ovl);
                float cxv = cx[(size_t)b * H_DIM + h];
                float cyv = fq * cxv + iq * c_t;
                float hyv = o_s * tanhf_(cyv);
                out[(size_t)b * H_DIM + h] = hyv;
                out[CY_OFF + (size_t)b * H_DIM + h] = cyv;
            }
        }
    }
}

// ================= fallback (R1 kernel) if ws too small =================
__global__ __launch_bounds__(THREADS, 2)
void onlstm_fused_fb(const float* __restrict__ x, const float* __restrict__ hx,
                     const float* __restrict__ cx,
                     const float* __restrict__ input_floor,
                     const float* __restrict__ forget_floor,
                     const float* __restrict__ W_ih, const float* __restrict__ b_ih,
                     const float* __restrict__ W_hh, const float* __restrict__ b_hh,
                     float* __restrict__ out)
{
    __shared__ __align__(16) __bf16 A_s[BM * BK];
    __shared__ __align__(16) __bf16 B_s[BN * BK];
    __shared__ float ci_s[BM], cf_s[BM], bias_s[BN];

    const int tid = threadIdx.x;
    const int bh  = blockIdx.x;
    const int bm  = blockIdx.y;
    const int h0  = bh * BNH;
    const int nc  = h0 >> 6;

    if (tid < BM) {
        {
            int g = tid >> 5, j = tid & 31;
            int wr = g * H_DIM + h0 + j;
            bias_s[tid] = b_ih[wr] + b_hh[wr];
        }
        int b = bm * BM + tid;
        const int off = (nc < 8) ? 0 : 8;
        const int ic  = (nc < 8) ? nc : (nc - 8);
        const float* pin = input_floor  + (size_t)b * NCHUNK + off;
        const float* pfg = forget_floor + (size_t)b * NCHUNK + off;
        float vi[8], vf[8];
        float mi = -1e30f, mf = -1e30f;
        #pragma unroll
        for (int t = 0; t < 8; ++t) {
            vi[t] = pin[t]; vf[t] = pfg[t];
            mi = fmaxf(mi, vi[t]); mf = fmaxf(mf, vf[t]);
        }
        float si = 0.f, sf = 0.f;
        #pragma unroll
        for (int t = 0; t < 8; ++t) {
            vi[t] = __expf(vi[t] - mi); vf[t] = __expf(vf[t] - mf);
            si += vi[t]; sf += vf[t];
        }
        float pi = 0.f, pf = 0.f;
        #pragma unroll
        for (int t = 0; t < 8; ++t) { if (t <= ic) { pi += vi[t]; pf += vf[t]; } }
        float suf_i = si - pi + vi[ic];
        float suf_f = sf - pf + vf[ic];
        float civ, cfv;
        if (nc < 8) { civ = pi / si;    cfv = suf_f / sf; }
        else        { civ = suf_i / si; cfv = pf / sf;    }
        ci_s[tid] = civ; cf_s[tid] = cfv;
    }

    f32x4 acc[2][8];
    #pragma unroll
    for (int i = 0; i < 2; ++i)
        #pragma unroll
        for (int j = 0; j < 8; ++j) acc[i][j] = (f32x4){0.f, 0.f, 0.f, 0.f};

    const int l  = tid & 63;
    const int w  = tid >> 6;
    const int lr = l & 15;
    const int lh = l >> 4;

    for (int kt = 0; kt < NKT; ++kt) {
        const float* Asrc; const float* Wsrc; int kb;
        if (kt < 16) { Asrc = x;  Wsrc = W_ih; kb = kt * BK; }
        else         { Asrc = hx; Wsrc = W_hh; kb = kt * BK - IN_DIM; }

        __syncthreads();
        #pragma unroll
        for (int i = 0; i < 8; ++i) {
            int idx = tid + i * THREADS;
            int row = idx >> 4;
            int k4  = (idx & 15) << 2;
            f32x4 v = *reinterpret_cast<const f32x4*>(
                Asrc + (size_t)(bm * BM + row) * IN_DIM + kb + k4);
            bf16x4 s4;
            s4.x = (__bf16)v.x; s4.y = (__bf16)v.y; s4.z = (__bf16)v.z; s4.w = (__bf16)v.w;
            *reinterpret_cast<bf16x4*>(&A_s[row * BK + (k4 ^ ((row & 7) << 3))]) = s4;
        }
        #pragma unroll
        for (int i = 0; i < 8; ++i) {
            int idx  = tid + i * THREADS;
            int nrow = idx >> 4;
            int k4   = (idx & 15) << 2;
            int wr   = (nrow >> 5) * H_DIM + h0 + (nrow & 31);
            f32x4 v = *reinterpret_cast<const f32x4*>(
                Wsrc + (size_t)wr * IN_DIM + kb + k4);
            bf16x4 s4;
            s4.x = (__bf16)v.x; s4.y = (__bf16)v.y; s4.z = (__bf16)v.z; s4.w = (__bf16)v.w;
            *reinterpret_cast<bf16x4*>(&B_s[nrow * BK + (k4 ^ ((nrow & 7) << 3))]) = s4;
        }
        __syncthreads();

        #pragma unroll
        for (int s = 0; s < 2; ++s) {
            const int kf = s * 32 + lh * 8;
            bf16x8 a0, a1;
            {
                int row = w * 32 + lr;
                a0 = *reinterpret_cast<const bf16x8*>(&A_s[row * BK + (kf ^ ((row & 7) << 3))]);
                row += 16;
                a1 = *reinterpret_cast<const bf16x8*>(&A_s[row * BK + (kf ^ ((row & 7) << 3))]);
            }
            #pragma unroll
            for (int fn = 0; fn < 8; ++fn) {
                int nrow = fn * 16 + lr;
                bf16x8 bb = *reinterpret_cast<const bf16x8*>(
                    &B_s[nrow * BK + (kf ^ ((nrow & 7) << 3))]);
                acc[0][fn] = __builtin_amdgcn_mfma_f32_16x16x32_bf16(a0, bb, acc[0][fn], 0, 0, 0);
                acc[1][fn] = __builtin_amdgcn_mfma_f32_16x16x32_bf16(a1, bb, acc[1][fn], 0, 0, 0);
            }
        }
    }

    const size_t CY_OFF = (size_t)B_ROWS * H_DIM;
    #pragma unroll
    for (int fm = 0; fm < 2; ++fm) {
        #pragma unroll
        for (int r = 0; r < 4; ++r) {
            int rt = w * 32 + fm * 16 + lh * 4 + r;
            int b  = bm * BM + rt;
            float civ = ci_s[rt], cfv = cf_s[rt];
            float ovl = cfv * civ;
            #pragma unroll
            for (int p = 0; p < 2; ++p) {
                int j = p * 16 + lr;
                int h = h0 + j;
                float og = acc[fm][0 + p][r] + bias_s[j];
                float cg = acc[fm][2 + p][r] + bias_s[32 + j];
                float ig = acc[fm][4 + p][r] + bias_s[64 + j];
                float fg = acc[fm][6 + p][r] + bias_s[96 + j];
                float i_s = sigmoidf_(ig);
                float f_s = sigmoidf_(fg);
                float c_t = tanhf_(cg);
                float o_s = sigmoidf_(og);
                float fq = f_s * ovl + (cfv - ovl);
                float iq = i_s * ovl + (civ - ovl);
                float cxv = cx[(size_t)b * H_DIM + h];
                float cyv = fq * cxv + iq * c_t;
                float hyv = o_s * tanhf_(cyv);
                out[(size_t)b * H_DIM + h] = hyv;
                out[CY_OFF + (size_t)b * H_DIM + h] = cyv;
            }
        }
    }
}

extern "C" void kernel_launch(void* const* d_in, const int* in_sizes, int n_in,
                              void* d_out, int out_size, void* d_ws, size_t ws_size,
                              hipStream_t stream) {
    const float* x            = (const float*)d_in[0];
    const float* hx           = (const float*)d_in[1];
    const float* cx           = (const float*)d_in[2];
    const float* input_floor  = (const float*)d_in[3];
    const float* forget_floor = (const float*)d_in[4];
    const float* W_ih         = (const float*)d_in[5];
    const float* b_ih         = (const float*)d_in[6];
    const float* W_hh         = (const float*)d_in[7];
    const float* b_hh         = (const float*)d_in[8];
    float* out = (float*)d_out;

    if (ws_size >= A_PACK_BYTES + W_PACK_BYTES) {
        __bf16* Abf = (__bf16*)d_ws;
        __bf16* Wp  = (__bf16*)((char*)d_ws + A_PACK_BYTES);
        pack_A<<<B_ROWS, 256, 0, stream>>>(x, hx, Abf);
        pack_W<<<(32 * 128 * 256) / 256, 256, 0, stream>>>(W_ih, W_hh, Wp);
        dim3 grid(H_DIM / BNH, B_ROWS / BM);   // (32, 64)
        onlstm_gemm<<<grid, THREADS, 0, stream>>>(
            Abf, Wp, cx, input_floor, forget_floor, b_ih, b_hh, out);
    } else {
        dim3 grid(H_DIM / BNH, B_ROWS / BM);
        onlstm_fused_fb<<<grid, THREADS, 0, stream>>>(
            x, hx, cx, input_floor, forget_floor, W_ih, b_ih, W_hh, b_hh, out);
    }
}